// Round 8
// baseline (261.586 us; speedup 1.0000x reference)
//
#include <hip/hip_runtime.h>
#include <math.h>

#define N1 16384

// Workspace layout (float offsets)
#define OFF_KEY   0L            // key bf16 [B][N1][64] = 8,388,608 shorts
#define OFF_WB    4194304L      // bf16 weights (21504 shorts, pad to 10752 floats)
#define OFF_CST   4205056L      // fp32: dwTf[576],o1[64],s2[64],o2[64], then 7x4096 transposed mats (29440)
#define OFF_POOL  4234496L      // 512   (zeroed)
#define OFF_PROT  4235008L      // 8192  (zeroed)
#define OFF_ZZ    4243200L      // 128   (zeroed)
#define OFF_OSUM  4243328L      // 12288 (zeroed)  [b*8+h][16 q][12]
#define OFF_QP    4255616L      // 8192
#define OFF_QB    4263808L      // 8192

typedef __attribute__((ext_vector_type(8))) short bf16x8;
typedef __attribute__((ext_vector_type(4))) float floatx4;

#define MFMA16(a, b, c) __builtin_amdgcn_mfma_f32_16x16x32_bf16(a, b, c, 0, 0, 0)

__device__ __forceinline__ unsigned short f2bf(float f) {
    union { float f; unsigned u; } v; v.f = f;
    unsigned r = v.u + 0x7fffu + ((v.u >> 16) & 1u);
    return (unsigned short)(r >> 16);
}
__device__ __forceinline__ float bf2f(unsigned short s) {
    union { unsigned u; float f; } v; v.u = ((unsigned)s) << 16;
    return v.f;
}
__device__ __forceinline__ float sigmoidf_(float x) { return 1.f / (1.f + __expf(-x)); }
__device__ __forceinline__ bf16x8 ldg8b(const unsigned short* p) { return *(const bf16x8*)p; }
__device__ __forceinline__ void unpack8(uint4 v, float* f) {
    f[0] = bf2f((unsigned short)(v.x & 0xffff)); f[1] = bf2f((unsigned short)(v.x >> 16));
    f[2] = bf2f((unsigned short)(v.y & 0xffff)); f[3] = bf2f((unsigned short)(v.y >> 16));
    f[4] = bf2f((unsigned short)(v.z & 0xffff)); f[5] = bf2f((unsigned short)(v.z >> 16));
    f[6] = bf2f((unsigned short)(v.w & 0xffff)); f[7] = bf2f((unsigned short)(v.w >> 16));
}

// ---------------------------------------------------------------- stage1: key+pool (blocks 0..4095) | prep (4096..4326)
__global__ __launch_bounds__(256) void k_stage1(
        const float* __restrict__ mem, const float* __restrict__ pos,
        const float* __restrict__ m1lw1, const float* __restrict__ m1lw2,
        const float* __restrict__ w_in, const float* __restrict__ pw,
        const float* __restrict__ mh, const float* __restrict__ dw_w,
        const float* __restrict__ bn1_g, const float* __restrict__ bn1_b,
        const float* __restrict__ bn1_m, const float* __restrict__ bn1_v,
        const float* __restrict__ bn2_g, const float* __restrict__ bn2_b,
        const float* __restrict__ bn2_m, const float* __restrict__ bn2_v,
        const float* __restrict__ m1gw1, const float* __restrict__ m1gw2,
        const float* __restrict__ m2gw1, const float* __restrict__ m2gw2,
        const float* __restrict__ m2lw1, const float* __restrict__ m2lw2,
        const float* __restrict__ w_out,
        const float* __restrict__ tgt, const float* __restrict__ qpos,
        const float* __restrict__ b_in,
        unsigned short* __restrict__ key, float* __restrict__ pool1raw,
        unsigned short* __restrict__ wb, float* __restrict__ cst,
        float* __restrict__ qp, float* __restrict__ queryb) {
    int tid = threadIdx.x;
    if (blockIdx.x < 4096) {
        __shared__ float sh[16][64];
        int b = blockIdx.x >> 9;
        int n_base = (blockIdx.x & 511) * 32;
        int c8 = tid & 7, local_n = tid >> 3;
        int n = n_base + local_n;
        long s4 = ((long)n * 8 + b) * 16 + c8 * 2;
        float4 m0 = ((const float4*)mem)[s4], m1 = ((const float4*)mem)[s4 + 1];
        float4 p0 = ((const float4*)pos)[s4], p1 = ((const float4*)pos)[s4 + 1];
        float f[8];
        f[0] = m0.x + p0.x; f[1] = m0.y + p0.y; f[2] = m0.z + p0.z; f[3] = m0.w + p0.w;
        f[4] = m1.x + p1.x; f[5] = m1.y + p1.y; f[6] = m1.z + p1.z; f[7] = m1.w + p1.w;
        uint4 o;
        o.x = (unsigned)f2bf(f[0]) | ((unsigned)f2bf(f[1]) << 16);
        o.y = (unsigned)f2bf(f[2]) | ((unsigned)f2bf(f[3]) << 16);
        o.z = (unsigned)f2bf(f[4]) | ((unsigned)f2bf(f[5]) << 16);
        o.w = (unsigned)f2bf(f[6]) | ((unsigned)f2bf(f[7]) << 16);
        ((uint4*)key)[(long)(b * 16384 + n) * 8 + c8] = o;
        int parity = (n_base >> 7) & 1;
        if (parity) {
            if (local_n & 1) {
                #pragma unroll
                for (int j = 0; j < 8; j++) sh[local_n >> 1][c8 * 8 + j] = f[j];
            }
            __syncthreads();
            if (tid < 64) {
                float s = 0.f;
                #pragma unroll
                for (int k = 0; k < 16; k++) s += sh[k][tid];
                atomicAdd(pool1raw + b * 64 + tid, s);
            }
        }
        return;
    }
    int blk = blockIdx.x - 4096;
    if (blk < 84) {
        int i = blk * 256 + tid;
        float v;
        if (i < 4096) v = m1lw1[i];
        else if (i < 8192) v = m1lw2[i - 4096];
        else if (i < 16384) v = w_in[4096 + (i - 8192)];
        else if (i < 20480) v = pw[i - 16384];
        else v = mh[i - 20480];
        wb[i] = f2bf(v);
    } else if (blk < 199) {
        int j = (blk - 84) * 256 + tid;   // < 29440
        float v;
        if (j < 576) {
            int k = j >> 6, c = j & 63;
            float s1 = bn1_g[c] * rsqrtf(bn1_v[c] + 1e-5f);
            v = dw_w[c * 9 + k] * s1;
        } else if (j < 640) {
            int c = j - 576;
            float s1 = bn1_g[c] * rsqrtf(bn1_v[c] + 1e-5f);
            v = bn1_b[c] - bn1_m[c] * s1;
        } else if (j < 704) {
            int c = j - 640;
            v = bn2_g[c] * rsqrtf(bn2_v[c] + 1e-5f);
        } else if (j < 768) {
            int c = j - 704;
            float s2 = bn2_g[c] * rsqrtf(bn2_v[c] + 1e-5f);
            v = bn2_b[c] - bn2_m[c] * s2;
        } else {
            int jj = j - 768;
            int m = jj >> 12, idx = jj & 4095;
            int sidx = (idx & 63) * 64 + (idx >> 6);   // transpose
            const float* src;
            switch (m) {
                case 0: src = m1gw1; break;
                case 1: src = m1gw2; break;
                case 2: src = m2gw1; break;
                case 3: src = m2gw2; break;
                case 4: src = m2lw1; break;
                case 5: src = m2lw2; break;
                default: src = w_out; break;
            }
            v = src[sidx];
        }
        cst[j] = v;
    } else {
        __shared__ float qv[4][64];
        int g = tid >> 6, lane = tid & 63;
        int u = (blk - 199) * 4 + g;
        int b = u >> 4, q = u & 15;
        long src = ((long)q * 8 + b) * 64 + lane;
        float v = tgt[src] + qpos[src];
        qv[g][lane] = v;
        queryb[(b * 16 + q) * 64 + lane] = v;
        __syncthreads();
        float acc = b_in[lane];
        for (int cc = 0; cc < 64; cc++) acc += qv[g][cc] * w_in[lane * 64 + cc];
        qp[(b * 16 + q) * 64 + lane] = acc;
    }
}

// ---------------------------------------------------------------- stage2: mscw1+attention (0..511) | dsconv (512..1535)
__global__ __launch_bounds__(512) void k_stage2(
        const unsigned short* __restrict__ keyb,
        const float* __restrict__ pool1raw,
        const float* __restrict__ lb1, const float* __restrict__ lb2,
        const float* __restrict__ gb1, const float* __restrict__ gb2,
        const float* __restrict__ b_in,
        const unsigned short* __restrict__ wb,
        const float* __restrict__ cst,
        const float* __restrict__ qp,
        float* __restrict__ osum,
        float* __restrict__ protos, float* __restrict__ Z) {
    __shared__ __align__(16) char smem[63488];
    int tid = threadIdx.x;
    int w = tid >> 6, l = tid & 63;
    if (blockIdx.x < 512) {
        // ---------------- mscw1 + fused attention
        short* stage = (short*)smem;               // 256*72 shorts = 36864 B
        short* hbuf  = (short*)(smem + 36864);     // 64*72
        short* wbuf  = (short*)(smem + 46080);     // 64*72
        float* parr  = (float*)(smem + 55296);
        float* gtmp  = parr + 64;
        float* gbuf  = parr + 128;
        float* qs    = (float*)(smem + 56064);     // [16][68] padded, 4352 B
        int b = blockIdx.x >> 6, tile = blockIdx.x & 63;
        int pairw = w >> 1, ch2 = w & 1;
        int m0 = pairw * 16, trow = l & 15, oct = l >> 4;
        const float* gw1T = cst + 768;
        const float* gw2T = cst + 4864;
        if (tid < 64) parr[tid] = pool1raw[b * 64 + tid] * (2.0f / 4096.0f);
        // qs staging (padded stride 68)
        {
            int i0 = tid;
            qs[(i0 >> 6) * 68 + (i0 & 63)] = qp[(b * 16 + (i0 >> 6)) * 64 + (i0 & 63)];
            int i1 = tid + 512;
            qs[(i1 >> 6) * 68 + (i1 & 63)] = qp[(b * 16 + (i1 >> 6)) * 64 + (i1 & 63)];
        }
        const unsigned short* src = keyb + ((long)b * 16384 + tile * 256) * 64;
        #pragma unroll
        for (int k = 0; k < 4; k++) {
            int u = k * 512 + tid;          // 2048 uint4
            int p = u >> 3, o = u & 7;
            uint4 v = *(const uint4*)(src + (long)u * 8);
            *(uint4*)(stage + p * 72 + o * 8) = v;
        }
        __syncthreads();   // sync1
        if (tid < 64) {
            float a = gb1[tid];
            for (int cc = 0; cc < 64; cc++) a += parr[cc] * gw1T[cc * 64 + tid];
            gtmp[tid] = fmaxf(a, 0.f);
        }
        int j = m0 + trow;
        float x[16], S[16];
        bf16x8 ax[2];
        #pragma unroll
        for (int half = 0; half < 2; half++) {
            int o = oct + half * 4;
            uint4 fa4 = *(const uint4*)(stage + (2 * j) * 72 + o * 8);
            uint4 fb4 = *(const uint4*)(stage + (2 * j + 1) * 72 + o * 8);
            uint4 fc4 = *(const uint4*)(stage + (128 + 2 * j) * 72 + o * 8);
            uint4 fd4 = *(const uint4*)(stage + (129 + 2 * j) * 72 + o * 8);
            float A[8], B[8], C[8], D[8];
            unpack8(fa4, A); unpack8(fb4, B); unpack8(fc4, C); unpack8(fd4, D);
            #pragma unroll
            for (int jj = 0; jj < 8; jj++) {
                float xd = 2.f * D[jj];
                x[half * 8 + jj] = xd;
                S[half * 8 + jj] = 0.5f * (A[jj] + B[jj] + C[jj] + D[jj]);
                ax[half][jj] = (short)f2bf(xd);
            }
        }
        const unsigned short* w1b = wb;
        const unsigned short* w2b = wb + 4096;
        const unsigned short* wkb = wb + 8192;
        const unsigned short* wvb = wb + 12288;
        // G1: hid = relu(x @ w1^T + b1), col tiles split by ch2
        #pragma unroll
        for (int t4i = 0; t4i < 2; t4i++) {
            int n = (ch2 * 2 + t4i) * 16 + trow;
            float bias = lb1[n];
            floatx4 acc = {bias, bias, bias, bias};
            acc = MFMA16(ax[0], ldg8b(w1b + n * 64 + oct * 8), acc);
            acc = MFMA16(ax[1], ldg8b(w1b + n * 64 + 32 + oct * 8), acc);
            #pragma unroll
            for (int r = 0; r < 4; r++)
                hbuf[(m0 + oct * 4 + r) * 72 + n] = (short)f2bf(fmaxf(acc[r], 0.f));
        }
        __syncthreads();   // sync2
        if (tid < 64) {
            float g = gb2[tid];
            for (int hh = 0; hh < 64; hh++) g += gtmp[hh] * gw2T[hh * 64 + tid];
            gbuf[tid] = g;
        }
        __syncthreads();   // sync2b
        // G2: wei = sigmoid(hid @ w2^T + b2 + glo)
        {
            bf16x8 ah0 = *(const bf16x8*)(hbuf + (m0 + trow) * 72 + oct * 8);
            bf16x8 ah1 = *(const bf16x8*)(hbuf + (m0 + trow) * 72 + 32 + oct * 8);
            #pragma unroll
            for (int t4i = 0; t4i < 2; t4i++) {
                int n = (ch2 * 2 + t4i) * 16 + trow;
                float bias = lb2[n];
                floatx4 acc = {bias, bias, bias, bias};
                acc = MFMA16(ah0, ldg8b(w2b + n * 64 + oct * 8), acc);
                acc = MFMA16(ah1, ldg8b(w2b + n * 64 + 32 + oct * 8), acc);
                float g = gbuf[n];
                #pragma unroll
                for (int r = 0; r < 4; r++)
                    wbuf[(m0 + oct * 4 + r) * 72 + n] = (short)f2bf(sigmoidf_(acc[r] + g));
            }
        }
        __syncthreads();   // sync3
        bf16x8 af0, af1;
        {
            bf16x8 w0 = *(const bf16x8*)(wbuf + (m0 + trow) * 72 + oct * 8);
            bf16x8 w1v = *(const bf16x8*)(wbuf + (m0 + trow) * 72 + 32 + oct * 8);
            #pragma unroll
            for (int jj = 0; jj < 8; jj++) {
                float we0 = bf2f((unsigned short)w0[jj]);
                float we1 = bf2f((unsigned short)w1v[jj]);
                af0[jj] = (short)f2bf(we0 * x[jj] + (1.f - we0) * S[jj]);
                af1[jj] = (short)f2bf(we1 * x[8 + jj] + (1.f - we1) * S[8 + jj]);
            }
        }
        __syncthreads();   // sync4: reuse hbuf/wbuf as kbuf/vbuf
        short* kbuf = hbuf; short* vbuf = wbuf;
        #pragma unroll
        for (int t4i = 0; t4i < 2; t4i++) {
            int ko = (ch2 * 2 + t4i) * 16 + trow;
            float bk = b_in[64 + ko], bv = b_in[128 + ko];
            floatx4 ak = {bk, bk, bk, bk};
            floatx4 av = {bv, bv, bv, bv};
            ak = MFMA16(af0, ldg8b(wkb + ko * 64 + oct * 8), ak);
            ak = MFMA16(af1, ldg8b(wkb + ko * 64 + 32 + oct * 8), ak);
            av = MFMA16(af0, ldg8b(wvb + ko * 64 + oct * 8), av);
            av = MFMA16(af1, ldg8b(wvb + ko * 64 + 32 + oct * 8), av);
            #pragma unroll
            for (int r = 0; r < 4; r++) {
                int row = m0 + oct * 4 + r;
                kbuf[row * 72 + ko] = (short)f2bf(ak[r]);
                vbuf[row * 72 + ko] = (short)f2bf(av[r]);
            }
        }
        __syncthreads();   // sync5: kbuf/vbuf ready
        // fused attention: wave = head, lane = (q, grp); no-max softmax partial sums
        {
            int h = w;
            int q = l & 15, grp = l >> 4;
            float qf[8];
            #pragma unroll
            for (int d = 0; d < 8; d++) qf[d] = qs[q * 68 + h * 8 + d];
            const float scale = 0.35355339059327373f;
            float lsum = 0.f, acc[8];
            #pragma unroll
            for (int d = 0; d < 8; d++) acc[d] = 0.f;
            #pragma unroll
            for (int ti = 0; ti < 16; ti++) {
                int tok = grp * 16 + ti;
                uint4 k4 = *(const uint4*)(kbuf + tok * 72 + h * 8);
                uint4 v4 = *(const uint4*)(vbuf + tok * 72 + h * 8);
                float kf[8], vf[8];
                unpack8(k4, kf); unpack8(v4, vf);
                float s = qf[0] * kf[0] + qf[1] * kf[1] + qf[2] * kf[2] + qf[3] * kf[3]
                        + qf[4] * kf[4] + qf[5] * kf[5] + qf[6] * kf[6] + qf[7] * kf[7];
                float e = __expf(s * scale);
                lsum += e;
                #pragma unroll
                for (int d = 0; d < 8; d++) acc[d] += e * vf[d];
            }
            lsum += __shfl_xor(lsum, 16);
            lsum += __shfl_xor(lsum, 32);
            #pragma unroll
            for (int d = 0; d < 8; d++) {
                acc[d] += __shfl_xor(acc[d], 16);
                acc[d] += __shfl_xor(acc[d], 32);
            }
            if (grp == 0) {
                float* P = osum + ((long)((b * 8 + h) * 16 + q)) * 12;
                atomicAdd(P, lsum);
                #pragma unroll
                for (int d = 0; d < 8; d++) atomicAdd(P + 1 + d, acc[d]);
            }
        }
        return;
    }
    // ---------------- dsconv
    {
        short* stage = (short*)smem;                       // 3*128*72 shorts
        short* pbuf  = (short*)(smem + 55296);             // 16*136
        float* cbuf  = (float*)(smem + 55296 + 4352);      // 768
        float* zred  = (float*)(smem + 55296 + 4352 + 3072); // [8][16]
        int blk = blockIdx.x - 512;
        int b = blk >> 7, h = blk & 127;
        int p0 = w * 16, pr = l & 15, oct = l >> 4;
        for (int k = tid; k < 768; k += 512) cbuf[k] = cst[k];
        const unsigned short* kb = keyb + (long)b * 1048576;
        #pragma unroll
        for (int r = 0; r < 3; r++) {
            int row = h - 1 + r;
            if ((unsigned)row < 128u) {
                const unsigned short* src = kb + (long)row * 8192;
                #pragma unroll
                for (int k = 0; k < 2; k++) {       // 1024 uint4 per row
                    int u = k * 512 + tid;
                    int p = u >> 3, o = u & 7;
                    uint4 v = *(const uint4*)(src + (long)u * 8);
                    *(uint4*)(stage + (r * 128 + p) * 72 + o * 8) = v;
                }
            } else {
                uint4 zz = {0u, 0u, 0u, 0u};
                #pragma unroll
                for (int k = 0; k < 2; k++) {
                    int u = k * 512 + tid;
                    int p = u >> 3, o = u & 7;
                    *(uint4*)(stage + (r * 128 + p) * 72 + o * 8) = zz;
                }
            }
        }
        __syncthreads();
        // dw conv 3x3 from LDS
        float accf[2][8];
        #pragma unroll
        for (int half = 0; half < 2; half++)
            #pragma unroll
            for (int jj = 0; jj < 8; jj++) accf[half][jj] = 0.f;
        #pragma unroll
        for (int r = 0; r < 3; r++) {
            #pragma unroll
            for (int kk = 0; kk < 3; kk++) {
                int col = p0 + pr - 1 + kk;
                if ((unsigned)col < 128u) {
                    #pragma unroll
                    for (int half = 0; half < 2; half++) {
                        int o = oct + half * 4;
                        uint4 d4 = *(const uint4*)(stage + (r * 128 + col) * 72 + o * 8);
                        float f[8]; unpack8(d4, f);
                        float4 wa = *(const float4*)(cbuf + (r * 3 + kk) * 64 + o * 8);
                        float4 wc = *(const float4*)(cbuf + (r * 3 + kk) * 64 + o * 8 + 4);
                        accf[half][0] += f[0] * wa.x; accf[half][1] += f[1] * wa.y;
                        accf[half][2] += f[2] * wa.z; accf[half][3] += f[3] * wa.w;
                        accf[half][4] += f[4] * wc.x; accf[half][5] += f[5] * wc.y;
                        accf[half][6] += f[6] * wc.z; accf[half][7] += f[7] * wc.w;
                    }
                }
            }
        }
        bf16x8 af[2];
        #pragma unroll
        for (int half = 0; half < 2; half++) {
            int o = oct + half * 4;
            float4 oa = *(const float4*)(cbuf + 576 + o * 8);
            float4 ob = *(const float4*)(cbuf + 576 + o * 8 + 4);
            af[half][0] = (short)f2bf(fmaxf(accf[half][0] + oa.x, 0.f));
            af[half][1] = (short)f2bf(fmaxf(accf[half][1] + oa.y, 0.f));
            af[half][2] = (short)f2bf(fmaxf(accf[half][2] + oa.z, 0.f));
            af[half][3] = (short)f2bf(fmaxf(accf[half][3] + oa.w, 0.f));
            af[half][4] = (short)f2bf(fmaxf(accf[half][4] + ob.x, 0.f));
            af[half][5] = (short)f2bf(fmaxf(accf[half][5] + ob.y, 0.f));
            af[half][6] = (short)f2bf(fmaxf(accf[half][6] + ob.z, 0.f));
            af[half][7] = (short)f2bf(fmaxf(accf[half][7] + ob.w, 0.f));
        }
        __syncthreads();   // conv reads done
        short* y2buf = stage;
        short* KT = stage + 18432;
        {
            const unsigned short* pwb = wb + 16384;
            #pragma unroll
            for (int t4 = 0; t4 < 4; t4++) {
                int n = t4 * 16 + pr;
                floatx4 acc = {0.f, 0.f, 0.f, 0.f};
                acc = MFMA16(af[0], ldg8b(pwb + n * 64 + oct * 8), acc);
                acc = MFMA16(af[1], ldg8b(pwb + n * 64 + 32 + oct * 8), acc);
                float s2 = cbuf[640 + n], o2 = cbuf[704 + n];
                #pragma unroll
                for (int r = 0; r < 4; r++)
                    y2buf[(p0 + oct * 4 + r) * 72 + n] = (short)f2bf(fmaxf(acc[r] * s2 + o2, 0.f));
            }
            // transpose center row -> KT[c][n ^ ((c>>3)<<3)]
            #pragma unroll
            for (int k2 = 0; k2 < 2; k2++) {
                int u = k2 * 512 + tid;          // 1024 uint4
                int n = u >> 3, o = u & 7;
                uint4 v = *(const uint4*)(stage + (128 + n) * 72 + o * 8);
                int nx = n ^ (o << 3);
                KT[(o * 8 + 0) * 136 + nx] = (short)(v.x & 0xffff);
                KT[(o * 8 + 1) * 136 + nx] = (short)(v.x >> 16);
                KT[(o * 8 + 2) * 136 + nx] = (short)(v.y & 0xffff);
                KT[(o * 8 + 3) * 136 + nx] = (short)(v.y >> 16);
                KT[(o * 8 + 4) * 136 + nx] = (short)(v.z & 0xffff);
                KT[(o * 8 + 5) * 136 + nx] = (short)(v.z >> 16);
                KT[(o * 8 + 6) * 136 + nx] = (short)(v.w & 0xffff);
                KT[(o * 8 + 7) * 136 + nx] = (short)(v.w >> 16);
            }
        }
        __syncthreads();
        // mask head + exp
        {
            const unsigned short* mhb = wb + 20480;
            bf16x8 a0 = *(const bf16x8*)(y2buf + (p0 + pr) * 72 + oct * 8);
            bf16x8 a1 = *(const bf16x8*)(y2buf + (p0 + pr) * 72 + 32 + oct * 8);
            floatx4 lg = {0.f, 0.f, 0.f, 0.f};
            lg = MFMA16(a0, ldg8b(mhb + pr * 64 + oct * 8), lg);
            lg = MFMA16(a1, ldg8b(mhb + pr * 64 + 32 + oct * 8), lg);
            float zs = 0.f;
            #pragma unroll
            for (int r = 0; r < 4; r++) {
                float e = __expf(lg[r]);
                zs += e;
                pbuf[pr * 136 + p0 + oct * 4 + r] = (short)f2bf(e);
            }
            zs += __shfl_xor(zs, 16);
            zs += __shfl_xor(zs, 32);
            if (l < 16) zred[w * 16 + l] = zs;
        }
        __syncthreads();
        // protos partial (waves 0-3) + Z atomic
        if (w < 4) {
            int c = w * 16 + pr;
            int xrc = ((c >> 3) & 7) << 3;
            floatx4 acc = {0.f, 0.f, 0.f, 0.f};
            #pragma unroll
            for (int s = 0; s < 4; s++) {
                bf16x8 A = *(const bf16x8*)(pbuf + pr * 136 + s * 32 + oct * 8);
                bf16x8 B = *(const bf16x8*)(KT + c * 136 + ((s * 32 + oct * 8) ^ xrc));
                acc = MFMA16(A, B, acc);
            }
            #pragma unroll
            for (int r = 0; r < 4; r++)
                atomicAdd(protos + (b * 16 + oct * 4 + r) * 64 + c, acc[r]);
        }
        if (tid < 16) {
            float zt = 0.f;
            #pragma unroll
            for (int ww = 0; ww < 8; ww++) zt += zred[ww * 16 + tid];
            atomicAdd(Z + b * 16 + tid, zt);
        }
    }
}

// ---------------------------------------------------------------- final: one wave per (b,t)
__global__ __launch_bounds__(64) void k_final(
        const float* __restrict__ queryb, const float* __restrict__ protos,
        const float* __restrict__ Z, const float* __restrict__ osum,
        const float* __restrict__ cst,
        const float* __restrict__ b_out,
        const float* __restrict__ ln1_g, const float* __restrict__ ln1_b,
        const float* __restrict__ ln2_g, const float* __restrict__ ln2_b,
        const float* __restrict__ lb1, const float* __restrict__ lb2,
        const float* __restrict__ gb1, const float* __restrict__ gb2,
        float* __restrict__ out) {
    const float* gw1T = cst + 8960;
    const float* gw2T = cst + 13056;
    const float* lw1T = cst + 17152;
    const float* lw2T = cst + 21248;
    const float* woT  = cst + 25344;
    int b = blockIdx.x >> 4, t = blockIdx.x & 15;
    int c = threadIdx.x;
    __shared__ float pool[64], xsrow[64], hid[64], hidg[64], osv[64];
    float q_own = queryb[(long)(b * 16 + t) * 64 + c];
    float poolacc = 0.f, xin_own = 0.f;
    #pragma unroll
    for (int tt = 0; tt < 16; tt++) {
        float rz = 1.f / Z[b * 16 + tt];
        float xv = protos[(long)(b * 16 + tt) * 64 + c] * rz
                 + queryb[(long)(b * 16 + tt) * 64 + c];
        poolacc += xv;
        if (tt == t) xin_own = xv;
    }
    pool[c] = poolacc * (1.f / 16.f);
    xsrow[c] = xin_own;
    {
        int hh = c >> 3, d = c & 7;
        const float* P = osum + ((long)((b * 8 + hh) * 16 + t)) * 12;
        osv[c] = P[1 + d] / P[0];
    }
    __syncthreads();
    // glo hidden + loc hidden
    {
        float a = gb1[c], a2 = lb1[c];
        for (int cc = 0; cc < 64; cc++) {
            a  += pool[cc]  * gw1T[cc * 64 + c];
            a2 += xsrow[cc] * lw1T[cc * 64 + c];
        }
        hidg[c] = fmaxf(a, 0.f);
        hid[c]  = fmaxf(a2, 0.f);
    }
    __syncthreads();
    float glo = gb2[c], loc = lb2[c];
    for (int hh = 0; hh < 64; hh++) {
        glo += hidg[hh] * gw2T[hh * 64 + c];
        loc += hid[hh]  * lw2T[hh * 64 + c];
    }
    float attn2 = sigmoidf_(loc + glo);
    float x2p = q_own * attn2 + q_own;
    float mu = x2p;
    for (int off = 32; off; off >>= 1) mu += __shfl_down(mu, off);
    mu = __shfl(mu, 0) * (1.f / 64.f);
    float d0 = x2p - mu;
    float vv = d0 * d0;
    for (int off = 32; off; off >>= 1) vv += __shfl_down(vv, off);
    vv = __shfl(vv, 0) * (1.f / 64.f);
    float x2 = d0 * rsqrtf(vv + 1e-5f) * ln2_g[c] + ln2_b[c];
    float x1p = b_out[c];
    for (int k = 0; k < 64; k++) x1p += osv[k] * woT[k * 64 + c];
    x1p += q_own;
    float mu1 = x1p;
    for (int off = 32; off; off >>= 1) mu1 += __shfl_down(mu1, off);
    mu1 = __shfl(mu1, 0) * (1.f / 64.f);
    float d1 = x1p - mu1;
    float v1 = d1 * d1;
    for (int off = 32; off; off >>= 1) v1 += __shfl_down(v1, off);
    v1 = __shfl(v1, 0) * (1.f / 64.f);
    float x1 = d1 * rsqrtf(v1 + 1e-5f) * ln1_g[c] + ln1_b[c];
    out[((long)t * 8 + b) * 64 + c] = x1 + x2;
}

// ----------------------------------------------------------------
extern "C" void kernel_launch(void* const* d_in, const int* in_sizes, int n_in,
                              void* d_out, int out_size, void* d_ws, size_t ws_size,
                              hipStream_t stream) {
    const float* tgt       = (const float*)d_in[0];
    const float* memory    = (const float*)d_in[1];
    const float* pos       = (const float*)d_in[2];
    const float* query_pos = (const float*)d_in[3];
    const float* w_in      = (const float*)d_in[4];
    const float* b_in      = (const float*)d_in[5];
    const float* w_out     = (const float*)d_in[6];
    const float* b_out     = (const float*)d_in[7];
    const float* ln1_g     = (const float*)d_in[8];
    const float* ln1_b     = (const float*)d_in[9];
    const float* ln2_g     = (const float*)d_in[10];
    const float* ln2_b     = (const float*)d_in[11];
    const float* dw_w      = (const float*)d_in[12];
    const float* bn1_g     = (const float*)d_in[13];
    const float* bn1_b     = (const float*)d_in[14];
    const float* bn1_m     = (const float*)d_in[15];
    const float* bn1_v     = (const float*)d_in[16];
    const float* pw_w      = (const float*)d_in[17];
    const float* bn2_g     = (const float*)d_in[18];
    const float* bn2_b     = (const float*)d_in[19];
    const float* bn2_m     = (const float*)d_in[20];
    const float* bn2_v     = (const float*)d_in[21];
    const float* mheads    = (const float*)d_in[22];
    const float* m1_lw1 = (const float*)d_in[23];
    const float* m1_lb1 = (const float*)d_in[24];
    const float* m1_lw2 = (const float*)d_in[25];
    const float* m1_lb2 = (const float*)d_in[26];
    const float* m1_gw1 = (const float*)d_in[27];
    const float* m1_gb1 = (const float*)d_in[28];
    const float* m1_gw2 = (const float*)d_in[29];
    const float* m1_gb2 = (const float*)d_in[30];
    const float* m2_lw1 = (const float*)d_in[31];
    const float* m2_lb1 = (const float*)d_in[32];
    const float* m2_lw2 = (const float*)d_in[33];
    const float* m2_lb2 = (const float*)d_in[34];
    const float* m2_gw1 = (const float*)d_in[35];
    const float* m2_gb1 = (const float*)d_in[36];
    const float* m2_gw2 = (const float*)d_in[37];
    const float* m2_gb2 = (const float*)d_in[38];

    float* ws = (float*)d_ws;
    float* out = (float*)d_out;
    unsigned short* keyb = (unsigned short*)(ws + OFF_KEY);
    unsigned short* wb   = (unsigned short*)(ws + OFF_WB);

    // zero atomic regions (pool + protos + Z + osum, contiguous: 21120 floats)
    hipMemsetAsync(ws + OFF_POOL, 0, 21120 * sizeof(float), stream);

    k_stage1<<<4327, 256, 0, stream>>>(memory, pos,
                                       m1_lw1, m1_lw2, w_in, pw_w, mheads, dw_w,
                                       bn1_g, bn1_b, bn1_m, bn1_v,
                                       bn2_g, bn2_b, bn2_m, bn2_v,
                                       m1_gw1, m1_gw2, m2_gw1, m2_gw2,
                                       m2_lw1, m2_lw2, w_out,
                                       tgt, query_pos, b_in,
                                       keyb, ws + OFF_POOL, wb, ws + OFF_CST,
                                       ws + OFF_QP, ws + OFF_QB);
    k_stage2<<<1536, 512, 0, stream>>>(keyb, ws + OFF_POOL,
                                       m1_lb1, m1_lb2, m1_gb1, m1_gb2, b_in,
                                       wb, ws + OFF_CST, ws + OFF_QP,
                                       ws + OFF_OSUM, ws + OFF_PROT, ws + OFF_ZZ);
    k_final<<<128, 64, 0, stream>>>(ws + OFF_QB, ws + OFF_PROT, ws + OFF_ZZ, ws + OFF_OSUM,
                                    ws + OFF_CST, b_out,
                                    ln1_g, ln1_b, ln2_g, ln2_b,
                                    m2_lb1, m2_lb2, m2_gb1, m2_gb2,
                                    out);
}

// Round 9
// 239.704 us; speedup vs baseline: 1.0913x; 1.0913x over previous
//
#include <hip/hip_runtime.h>
#include <math.h>

#define N1 16384

// Workspace layout (float offsets)
#define OFF_KEY   0L            // key bf16 [B][N1][64] = 8,388,608 shorts
#define OFF_KPH   4194304L      // kp bf16 [B*H][4096][8]
#define OFF_VPH   5242880L
#define OFF_WB    6291456L      // bf16 weights (21504 shorts)
#define OFF_CST   6302208L      // fp32: dwTf[576],o1[64],s2[64],o2[64], then 7x4096 transposed mats
#define OFF_POOL  6331648L      // 512  (zeroed)
#define OFF_PROT  6332160L      // 8192 (zeroed)
#define OFF_ZZ    6340352L      // 128  (zeroed)
#define OFF_QP    6340480L
#define OFF_QB    6348672L
#define OFF_PART  6356864L      // [B*H][16 q][8 seg][12]

typedef __attribute__((ext_vector_type(8))) short bf16x8;
typedef __attribute__((ext_vector_type(4))) float floatx4;

#define MFMA16(a, b, c) __builtin_amdgcn_mfma_f32_16x16x32_bf16(a, b, c, 0, 0, 0)

__device__ __forceinline__ unsigned short f2bf(float f) {
    union { float f; unsigned u; } v; v.f = f;
    unsigned r = v.u + 0x7fffu + ((v.u >> 16) & 1u);
    return (unsigned short)(r >> 16);
}
__device__ __forceinline__ float bf2f(unsigned short s) {
    union { unsigned u; float f; } v; v.u = ((unsigned)s) << 16;
    return v.f;
}
__device__ __forceinline__ float sigmoidf_(float x) { return 1.f / (1.f + __expf(-x)); }
__device__ __forceinline__ bf16x8 ldg8b(const unsigned short* p) { return *(const bf16x8*)p; }
__device__ __forceinline__ void unpack8(uint4 v, float* f) {
    f[0] = bf2f((unsigned short)(v.x & 0xffff)); f[1] = bf2f((unsigned short)(v.x >> 16));
    f[2] = bf2f((unsigned short)(v.y & 0xffff)); f[3] = bf2f((unsigned short)(v.y >> 16));
    f[4] = bf2f((unsigned short)(v.z & 0xffff)); f[5] = bf2f((unsigned short)(v.z >> 16));
    f[6] = bf2f((unsigned short)(v.w & 0xffff)); f[7] = bf2f((unsigned short)(v.w >> 16));
}

// ---------------------------------------------------------------- stage1: key+pool (blocks 0..4095) | prep (4096..4326)
__global__ __launch_bounds__(256) void k_stage1(
        const float* __restrict__ mem, const float* __restrict__ pos,
        const float* __restrict__ m1lw1, const float* __restrict__ m1lw2,
        const float* __restrict__ w_in, const float* __restrict__ pw,
        const float* __restrict__ mh, const float* __restrict__ dw_w,
        const float* __restrict__ bn1_g, const float* __restrict__ bn1_b,
        const float* __restrict__ bn1_m, const float* __restrict__ bn1_v,
        const float* __restrict__ bn2_g, const float* __restrict__ bn2_b,
        const float* __restrict__ bn2_m, const float* __restrict__ bn2_v,
        const float* __restrict__ m1gw1, const float* __restrict__ m1gw2,
        const float* __restrict__ m2gw1, const float* __restrict__ m2gw2,
        const float* __restrict__ m2lw1, const float* __restrict__ m2lw2,
        const float* __restrict__ w_out,
        const float* __restrict__ tgt, const float* __restrict__ qpos,
        const float* __restrict__ b_in,
        unsigned short* __restrict__ key, float* __restrict__ pool1raw,
        unsigned short* __restrict__ wb, float* __restrict__ cst,
        float* __restrict__ qp, float* __restrict__ queryb) {
    int tid = threadIdx.x;
    if (blockIdx.x < 4096) {
        __shared__ float sh[16][64];
        int b = blockIdx.x >> 9;
        int n_base = (blockIdx.x & 511) * 32;
        int c8 = tid & 7, local_n = tid >> 3;
        int n = n_base + local_n;
        long s4 = ((long)n * 8 + b) * 16 + c8 * 2;
        float4 m0 = ((const float4*)mem)[s4], m1 = ((const float4*)mem)[s4 + 1];
        float4 p0 = ((const float4*)pos)[s4], p1 = ((const float4*)pos)[s4 + 1];
        float f[8];
        f[0] = m0.x + p0.x; f[1] = m0.y + p0.y; f[2] = m0.z + p0.z; f[3] = m0.w + p0.w;
        f[4] = m1.x + p1.x; f[5] = m1.y + p1.y; f[6] = m1.z + p1.z; f[7] = m1.w + p1.w;
        uint4 o;
        o.x = (unsigned)f2bf(f[0]) | ((unsigned)f2bf(f[1]) << 16);
        o.y = (unsigned)f2bf(f[2]) | ((unsigned)f2bf(f[3]) << 16);
        o.z = (unsigned)f2bf(f[4]) | ((unsigned)f2bf(f[5]) << 16);
        o.w = (unsigned)f2bf(f[6]) | ((unsigned)f2bf(f[7]) << 16);
        ((uint4*)key)[(long)(b * 16384 + n) * 8 + c8] = o;
        int parity = (n_base >> 7) & 1;
        if (parity) {
            if (local_n & 1) {
                #pragma unroll
                for (int j = 0; j < 8; j++) sh[local_n >> 1][c8 * 8 + j] = f[j];
            }
            __syncthreads();
            if (tid < 64) {
                float s = 0.f;
                #pragma unroll
                for (int k = 0; k < 16; k++) s += sh[k][tid];
                atomicAdd(pool1raw + b * 64 + tid, s);
            }
        }
        return;
    }
    int blk = blockIdx.x - 4096;
    if (blk < 84) {
        int i = blk * 256 + tid;
        float v;
        if (i < 4096) v = m1lw1[i];
        else if (i < 8192) v = m1lw2[i - 4096];
        else if (i < 16384) v = w_in[4096 + (i - 8192)];
        else if (i < 20480) v = pw[i - 16384];
        else v = mh[i - 20480];
        wb[i] = f2bf(v);
    } else if (blk < 199) {
        int j = (blk - 84) * 256 + tid;   // < 29440
        float v;
        if (j < 576) {
            int k = j >> 6, c = j & 63;
            float s1 = bn1_g[c] * rsqrtf(bn1_v[c] + 1e-5f);
            v = dw_w[c * 9 + k] * s1;
        } else if (j < 640) {
            int c = j - 576;
            float s1 = bn1_g[c] * rsqrtf(bn1_v[c] + 1e-5f);
            v = bn1_b[c] - bn1_m[c] * s1;
        } else if (j < 704) {
            int c = j - 640;
            v = bn2_g[c] * rsqrtf(bn2_v[c] + 1e-5f);
        } else if (j < 768) {
            int c = j - 704;
            float s2 = bn2_g[c] * rsqrtf(bn2_v[c] + 1e-5f);
            v = bn2_b[c] - bn2_m[c] * s2;
        } else {
            int jj = j - 768;
            int m = jj >> 12, idx = jj & 4095;
            int sidx = (idx & 63) * 64 + (idx >> 6);   // transpose
            const float* src;
            switch (m) {
                case 0: src = m1gw1; break;
                case 1: src = m1gw2; break;
                case 2: src = m2gw1; break;
                case 3: src = m2gw2; break;
                case 4: src = m2lw1; break;
                case 5: src = m2lw2; break;
                default: src = w_out; break;
            }
            v = src[sidx];
        }
        cst[j] = v;
    } else {
        __shared__ float qv[4][64];
        int g = tid >> 6, lane = tid & 63;
        int u = (blk - 199) * 4 + g;
        int b = u >> 4, q = u & 15;
        long src = ((long)q * 8 + b) * 64 + lane;
        float v = tgt[src] + qpos[src];
        qv[g][lane] = v;
        queryb[(b * 16 + q) * 64 + lane] = v;
        __syncthreads();
        float acc = b_in[lane];
        for (int cc = 0; cc < 64; cc++) acc += qv[g][cc] * w_in[lane * 64 + cc];
        qp[(b * 16 + q) * 64 + lane] = acc;
    }
}

// ---------------------------------------------------------------- stage2: mscw1 (blocks 0..511) | dsconv (512..1535)  [R6 proven body]
__global__ __launch_bounds__(512) void k_stage2(
        const unsigned short* __restrict__ keyb,
        const float* __restrict__ pool1raw,
        const float* __restrict__ lb1, const float* __restrict__ lb2,
        const float* __restrict__ gb1, const float* __restrict__ gb2,
        const float* __restrict__ b_in,
        const unsigned short* __restrict__ wb,
        const float* __restrict__ cst,
        unsigned short* __restrict__ kph, unsigned short* __restrict__ vph,
        float* __restrict__ protos, float* __restrict__ Z) {
    __shared__ __align__(16) char smem[63488];
    int tid = threadIdx.x;
    int w = tid >> 6, l = tid & 63;
    if (blockIdx.x < 512) {
        // ---------------- mscw1: 8 waves, wave-pairs split column tiles
        short* stage = (short*)smem;               // 256*72 shorts
        short* hbuf  = (short*)(smem + 36864);     // 64*72
        short* wbuf  = (short*)(smem + 46080);     // 64*72
        float* parr  = (float*)(smem + 55296);
        float* gtmp  = parr + 64;
        float* gbuf  = parr + 128;
        int b = blockIdx.x >> 6, tile = blockIdx.x & 63;
        int pairw = w >> 1, ch2 = w & 1;
        int m0 = pairw * 16, trow = l & 15, oct = l >> 4;
        const float* gw1T = cst + 768;
        const float* gw2T = cst + 4864;
        if (tid < 64) parr[tid] = pool1raw[b * 64 + tid] * (2.0f / 4096.0f);
        const unsigned short* src = keyb + ((long)b * 16384 + tile * 256) * 64;
        #pragma unroll
        for (int k = 0; k < 4; k++) {
            int u = k * 512 + tid;          // 2048 uint4
            int p = u >> 3, o = u & 7;
            uint4 v = *(const uint4*)(src + (long)u * 8);
            *(uint4*)(stage + p * 72 + o * 8) = v;
        }
        __syncthreads();   // sync1
        if (tid < 64) {
            float a = gb1[tid];
            for (int cc = 0; cc < 64; cc++) a += parr[cc] * gw1T[cc * 64 + tid];
            gtmp[tid] = fmaxf(a, 0.f);
        }
        int j = m0 + trow;
        float x[16], S[16];
        bf16x8 ax[2];
        #pragma unroll
        for (int half = 0; half < 2; half++) {
            int o = oct + half * 4;
            uint4 fa4 = *(const uint4*)(stage + (2 * j) * 72 + o * 8);
            uint4 fb4 = *(const uint4*)(stage + (2 * j + 1) * 72 + o * 8);
            uint4 fc4 = *(const uint4*)(stage + (128 + 2 * j) * 72 + o * 8);
            uint4 fd4 = *(const uint4*)(stage + (129 + 2 * j) * 72 + o * 8);
            float A[8], B[8], C[8], D[8];
            unpack8(fa4, A); unpack8(fb4, B); unpack8(fc4, C); unpack8(fd4, D);
            #pragma unroll
            for (int jj = 0; jj < 8; jj++) {
                float xd = 2.f * D[jj];
                x[half * 8 + jj] = xd;
                S[half * 8 + jj] = 0.5f * (A[jj] + B[jj] + C[jj] + D[jj]);
                ax[half][jj] = (short)f2bf(xd);
            }
        }
        const unsigned short* w1b = wb;
        const unsigned short* w2b = wb + 4096;
        const unsigned short* wkb = wb + 8192;
        const unsigned short* wvb = wb + 12288;
        // G1: hid = relu(x @ w1^T + b1), col tiles split by ch2
        #pragma unroll
        for (int t4i = 0; t4i < 2; t4i++) {
            int n = (ch2 * 2 + t4i) * 16 + trow;
            float bias = lb1[n];
            floatx4 acc = {bias, bias, bias, bias};
            acc = MFMA16(ax[0], ldg8b(w1b + n * 64 + oct * 8), acc);
            acc = MFMA16(ax[1], ldg8b(w1b + n * 64 + 32 + oct * 8), acc);
            #pragma unroll
            for (int r = 0; r < 4; r++)
                hbuf[(m0 + oct * 4 + r) * 72 + n] = (short)f2bf(fmaxf(acc[r], 0.f));
        }
        __syncthreads();   // sync2
        if (tid < 64) {
            float g = gb2[tid];
            for (int hh = 0; hh < 64; hh++) g += gtmp[hh] * gw2T[hh * 64 + tid];
            gbuf[tid] = g;
        }
        __syncthreads();   // sync2b
        // G2: wei = sigmoid(hid @ w2^T + b2 + glo)
        {
            bf16x8 ah0 = *(const bf16x8*)(hbuf + (m0 + trow) * 72 + oct * 8);
            bf16x8 ah1 = *(const bf16x8*)(hbuf + (m0 + trow) * 72 + 32 + oct * 8);
            #pragma unroll
            for (int t4i = 0; t4i < 2; t4i++) {
                int n = (ch2 * 2 + t4i) * 16 + trow;
                float bias = lb2[n];
                floatx4 acc = {bias, bias, bias, bias};
                acc = MFMA16(ah0, ldg8b(w2b + n * 64 + oct * 8), acc);
                acc = MFMA16(ah1, ldg8b(w2b + n * 64 + 32 + oct * 8), acc);
                float g = gbuf[n];
                #pragma unroll
                for (int r = 0; r < 4; r++)
                    wbuf[(m0 + oct * 4 + r) * 72 + n] = (short)f2bf(sigmoidf_(acc[r] + g));
            }
        }
        __syncthreads();   // sync3
        bf16x8 af0, af1;
        {
            bf16x8 w0 = *(const bf16x8*)(wbuf + (m0 + trow) * 72 + oct * 8);
            bf16x8 w1v = *(const bf16x8*)(wbuf + (m0 + trow) * 72 + 32 + oct * 8);
            #pragma unroll
            for (int jj = 0; jj < 8; jj++) {
                float we0 = bf2f((unsigned short)w0[jj]);
                float we1 = bf2f((unsigned short)w1v[jj]);
                af0[jj] = (short)f2bf(we0 * x[jj] + (1.f - we0) * S[jj]);
                af1[jj] = (short)f2bf(we1 * x[8 + jj] + (1.f - we1) * S[8 + jj]);
            }
        }
        __syncthreads();   // sync4: reuse hbuf/wbuf as kbuf/vbuf
        short* kbuf = hbuf; short* vbuf = wbuf;
        #pragma unroll
        for (int t4i = 0; t4i < 2; t4i++) {
            int ko = (ch2 * 2 + t4i) * 16 + trow;
            float bk = b_in[64 + ko], bv = b_in[128 + ko];
            floatx4 ak = {bk, bk, bk, bk};
            floatx4 av = {bv, bv, bv, bv};
            ak = MFMA16(af0, ldg8b(wkb + ko * 64 + oct * 8), ak);
            ak = MFMA16(af1, ldg8b(wkb + ko * 64 + 32 + oct * 8), ak);
            av = MFMA16(af0, ldg8b(wvb + ko * 64 + oct * 8), av);
            av = MFMA16(af1, ldg8b(wvb + ko * 64 + 32 + oct * 8), av);
            #pragma unroll
            for (int r = 0; r < 4; r++) {
                int row = m0 + oct * 4 + r;
                kbuf[row * 72 + ko] = (short)f2bf(ak[r]);
                vbuf[row * 72 + ko] = (short)f2bf(av[r]);
            }
        }
        __syncthreads();   // sync5
        {
            int h = tid >> 6, tok = tid & 63;
            uint4 kk = *(const uint4*)(kbuf + tok * 72 + h * 8);
            uint4 vv = *(const uint4*)(vbuf + tok * 72 + h * 8);
            long du = (long)(b * 8 + h) * 4096 + tile * 64 + tok;
            ((uint4*)kph)[du] = kk;
            ((uint4*)vph)[du] = vv;
        }
        return;
    }
    // ---------------- dsconv: blocks 512..1535
    {
        short* stage = (short*)smem;                       // 3*128*72
        short* pbuf  = (short*)(smem + 55296);             // 16*136
        float* cbuf  = (float*)(smem + 55296 + 4352);      // 768
        float* zred  = (float*)(smem + 55296 + 4352 + 3072); // [8][16]
        int blk = blockIdx.x - 512;
        int b = blk >> 7, h = blk & 127;
        int p0 = w * 16, pr = l & 15, oct = l >> 4;
        for (int k = tid; k < 768; k += 512) cbuf[k] = cst[k];
        const unsigned short* kb = keyb + (long)b * 1048576;
        #pragma unroll
        for (int r = 0; r < 3; r++) {
            int row = h - 1 + r;
            if ((unsigned)row < 128u) {
                const unsigned short* src = kb + (long)row * 8192;
                #pragma unroll
                for (int k = 0; k < 2; k++) {       // 1024 uint4 per row
                    int u = k * 512 + tid;
                    int p = u >> 3, o = u & 7;
                    uint4 v = *(const uint4*)(src + (long)u * 8);
                    *(uint4*)(stage + (r * 128 + p) * 72 + o * 8) = v;
                }
            } else {
                uint4 zz = {0u, 0u, 0u, 0u};
                #pragma unroll
                for (int k = 0; k < 2; k++) {
                    int u = k * 512 + tid;
                    int p = u >> 3, o = u & 7;
                    *(uint4*)(stage + (r * 128 + p) * 72 + o * 8) = zz;
                }
            }
        }
        __syncthreads();
        // dw conv 3x3 from LDS
        float accf[2][8];
        #pragma unroll
        for (int half = 0; half < 2; half++)
            #pragma unroll
            for (int jj = 0; jj < 8; jj++) accf[half][jj] = 0.f;
        #pragma unroll
        for (int r = 0; r < 3; r++) {
            #pragma unroll
            for (int kk = 0; kk < 3; kk++) {
                int col = p0 + pr - 1 + kk;
                if ((unsigned)col < 128u) {
                    #pragma unroll
                    for (int half = 0; half < 2; half++) {
                        int o = oct + half * 4;
                        uint4 d4 = *(const uint4*)(stage + (r * 128 + col) * 72 + o * 8);
                        float f[8]; unpack8(d4, f);
                        float4 wa = *(const float4*)(cbuf + (r * 3 + kk) * 64 + o * 8);
                        float4 wc = *(const float4*)(cbuf + (r * 3 + kk) * 64 + o * 8 + 4);
                        accf[half][0] += f[0] * wa.x; accf[half][1] += f[1] * wa.y;
                        accf[half][2] += f[2] * wa.z; accf[half][3] += f[3] * wa.w;
                        accf[half][4] += f[4] * wc.x; accf[half][5] += f[5] * wc.y;
                        accf[half][6] += f[6] * wc.z; accf[half][7] += f[7] * wc.w;
                    }
                }
            }
        }
        bf16x8 af[2];
        #pragma unroll
        for (int half = 0; half < 2; half++) {
            int o = oct + half * 4;
            float4 oa = *(const float4*)(cbuf + 576 + o * 8);
            float4 ob = *(const float4*)(cbuf + 576 + o * 8 + 4);
            af[half][0] = (short)f2bf(fmaxf(accf[half][0] + oa.x, 0.f));
            af[half][1] = (short)f2bf(fmaxf(accf[half][1] + oa.y, 0.f));
            af[half][2] = (short)f2bf(fmaxf(accf[half][2] + oa.z, 0.f));
            af[half][3] = (short)f2bf(fmaxf(accf[half][3] + oa.w, 0.f));
            af[half][4] = (short)f2bf(fmaxf(accf[half][4] + ob.x, 0.f));
            af[half][5] = (short)f2bf(fmaxf(accf[half][5] + ob.y, 0.f));
            af[half][6] = (short)f2bf(fmaxf(accf[half][6] + ob.z, 0.f));
            af[half][7] = (short)f2bf(fmaxf(accf[half][7] + ob.w, 0.f));
        }
        __syncthreads();   // conv reads done
        short* y2buf = stage;
        short* KT = stage + 18432;
        {
            const unsigned short* pwb = wb + 16384;
            #pragma unroll
            for (int t4 = 0; t4 < 4; t4++) {
                int n = t4 * 16 + pr;
                floatx4 acc = {0.f, 0.f, 0.f, 0.f};
                acc = MFMA16(af[0], ldg8b(pwb + n * 64 + oct * 8), acc);
                acc = MFMA16(af[1], ldg8b(pwb + n * 64 + 32 + oct * 8), acc);
                float s2 = cbuf[640 + n], o2 = cbuf[704 + n];
                #pragma unroll
                for (int r = 0; r < 4; r++)
                    y2buf[(p0 + oct * 4 + r) * 72 + n] = (short)f2bf(fmaxf(acc[r] * s2 + o2, 0.f));
            }
            // transpose center row -> KT[c][n ^ ((c>>3)<<3)]
            #pragma unroll
            for (int k2 = 0; k2 < 2; k2++) {
                int u = k2 * 512 + tid;          // 1024 uint4
                int n = u >> 3, o = u & 7;
                uint4 v = *(const uint4*)(stage + (128 + n) * 72 + o * 8);
                int nx = n ^ (o << 3);
                KT[(o * 8 + 0) * 136 + nx] = (short)(v.x & 0xffff);
                KT[(o * 8 + 1) * 136 + nx] = (short)(v.x >> 16);
                KT[(o * 8 + 2) * 136 + nx] = (short)(v.y & 0xffff);
                KT[(o * 8 + 3) * 136 + nx] = (short)(v.y >> 16);
                KT[(o * 8 + 4) * 136 + nx] = (short)(v.z & 0xffff);
                KT[(o * 8 + 5) * 136 + nx] = (short)(v.z >> 16);
                KT[(o * 8 + 6) * 136 + nx] = (short)(v.w & 0xffff);
                KT[(o * 8 + 7) * 136 + nx] = (short)(v.w >> 16);
            }
        }
        __syncthreads();
        // mask head + exp
        {
            const unsigned short* mhb = wb + 20480;
            bf16x8 a0 = *(const bf16x8*)(y2buf + (p0 + pr) * 72 + oct * 8);
            bf16x8 a1 = *(const bf16x8*)(y2buf + (p0 + pr) * 72 + 32 + oct * 8);
            floatx4 lg = {0.f, 0.f, 0.f, 0.f};
            lg = MFMA16(a0, ldg8b(mhb + pr * 64 + oct * 8), lg);
            lg = MFMA16(a1, ldg8b(mhb + pr * 64 + 32 + oct * 8), lg);
            float zs = 0.f;
            #pragma unroll
            for (int r = 0; r < 4; r++) {
                float e = __expf(lg[r]);
                zs += e;
                pbuf[pr * 136 + p0 + oct * 4 + r] = (short)f2bf(e);
            }
            zs += __shfl_xor(zs, 16);
            zs += __shfl_xor(zs, 32);
            if (l < 16) zred[w * 16 + l] = zs;
        }
        __syncthreads();
        // protos partial (waves 0-3) + Z atomic
        if (w < 4) {
            int c = w * 16 + pr;
            int xrc = ((c >> 3) & 7) << 3;
            floatx4 acc = {0.f, 0.f, 0.f, 0.f};
            #pragma unroll
            for (int s = 0; s < 4; s++) {
                bf16x8 A = *(const bf16x8*)(pbuf + pr * 136 + s * 32 + oct * 8);
                bf16x8 B = *(const bf16x8*)(KT + c * 136 + ((s * 32 + oct * 8) ^ xrc));
                acc = MFMA16(A, B, acc);
            }
            #pragma unroll
            for (int r = 0; r < 4; r++)
                atomicAdd(protos + (b * 16 + oct * 4 + r) * 64 + c, acc[r]);
        }
        if (tid < 16) {
            float zt = 0.f;
            #pragma unroll
            for (int ww = 0; ww < 8; ww++) zt += zred[ww * 16 + tid];
            atomicAdd(Z + b * 16 + tid, zt);
        }
    }
}

// ---------------------------------------------------------------- K6: MHA partials, no-max softmax (bounded logits)
__global__ __launch_bounds__(256) void k_mha(const float* __restrict__ qp,
                                             const unsigned short* __restrict__ kph,
                                             const unsigned short* __restrict__ vph,
                                             float* __restrict__ part) {
    int bh = blockIdx.x >> 3, seg = blockIdx.x & 7;
    int b = bh >> 3, hh = bh & 7;
    int tid = threadIdx.x;
    int q = tid >> 4, sub = tid & 15;
    const float* qv = qp + (long)(b * 16 + q) * 64 + hh * 8;
    float4 q0 = ((const float4*)qv)[0];
    float4 q1 = ((const float4*)qv)[1];
    const uint4* K4 = (const uint4*)kph + (long)bh * 4096;
    const uint4* V4 = (const uint4*)vph + (long)bh * 4096;
    const float scale = 0.35355339059327373f;
    float lsum = 0.f;
    float acc[8];
    #pragma unroll
    for (int d = 0; d < 8; d++) acc[d] = 0.f;
    for (int i = 0; i < 32; i++) {
        int n = seg * 512 + i * 16 + sub;
        float k8[8]; unpack8(K4[n], k8);
        float s = q0.x * k8[0] + q0.y * k8[1] + q0.z * k8[2] + q0.w * k8[3]
                + q1.x * k8[4] + q1.y * k8[5] + q1.z * k8[6] + q1.w * k8[7];
        float e = __expf(s * scale);
        lsum += e;
        float v8[8]; unpack8(V4[n], v8);
        #pragma unroll
        for (int d = 0; d < 8; d++) acc[d] += e * v8[d];
    }
    #pragma unroll
    for (int off = 1; off < 16; off <<= 1) {
        lsum += __shfl_xor(lsum, off);
        #pragma unroll
        for (int d = 0; d < 8; d++) acc[d] += __shfl_xor(acc[d], off);
    }
    if (sub == 0) {
        float* P = part + ((long)(bh * 16 + q) * 8 + seg) * 12;
        P[0] = lsum;
        #pragma unroll
        for (int d = 0; d < 8; d++) P[1 + d] = acc[d];
    }
}

// ---------------------------------------------------------------- final: one wave per (b,t)
__global__ __launch_bounds__(64) void k_final(
        const float* __restrict__ queryb, const float* __restrict__ protos,
        const float* __restrict__ Z, const float* __restrict__ part,
        const float* __restrict__ cst,
        const float* __restrict__ b_out,
        const float* __restrict__ ln1_g, const float* __restrict__ ln1_b,
        const float* __restrict__ ln2_g, const float* __restrict__ ln2_b,
        const float* __restrict__ lb1, const float* __restrict__ lb2,
        const float* __restrict__ gb1, const float* __restrict__ gb2,
        float* __restrict__ out) {
    const float* gw1T = cst + 8960;
    const float* gw2T = cst + 13056;
    const float* lw1T = cst + 17152;
    const float* lw2T = cst + 21248;
    const float* woT  = cst + 25344;
    int b = blockIdx.x >> 4, t = blockIdx.x & 15;
    int c = threadIdx.x;
    __shared__ float pool[64], xsrow[64], hid[64], hidg[64], osv[64];
    float q_own = queryb[(long)(b * 16 + t) * 64 + c];
    float poolacc = 0.f, xin_own = 0.f;
    #pragma unroll
    for (int tt = 0; tt < 16; tt++) {
        float rz = 1.f / Z[b * 16 + tt];
        float xv = protos[(long)(b * 16 + tt) * 64 + c] * rz
                 + queryb[(long)(b * 16 + tt) * 64 + c];
        poolacc += xv;
        if (tt == t) xin_own = xv;
    }
    pool[c] = poolacc * (1.f / 16.f);
    xsrow[c] = xin_own;
    {
        int hh = c >> 3, d = c & 7;
        const float* P = part + ((long)((b * 8 + hh) * 16 + t) * 8) * 12;
        float ll = 0.f, aa = 0.f;
        #pragma unroll
        for (int s = 0; s < 8; s++) {
            ll += P[s * 12];
            aa += P[s * 12 + 1 + d];
        }
        osv[c] = aa / ll;
    }
    __syncthreads();
    // glo hidden + loc hidden
    {
        float a = gb1[c], a2 = lb1[c];
        for (int cc = 0; cc < 64; cc++) {
            a  += pool[cc]  * gw1T[cc * 64 + c];
            a2 += xsrow[cc] * lw1T[cc * 64 + c];
        }
        hidg[c] = fmaxf(a, 0.f);
        hid[c]  = fmaxf(a2, 0.f);
    }
    __syncthreads();
    float glo = gb2[c], loc = lb2[c];
    for (int hh = 0; hh < 64; hh++) {
        glo += hidg[hh] * gw2T[hh * 64 + c];
        loc += hid[hh]  * lw2T[hh * 64 + c];
    }
    float attn2 = sigmoidf_(loc + glo);
    float x2p = q_own * attn2 + q_own;
    float mu = x2p;
    for (int off = 32; off; off >>= 1) mu += __shfl_down(mu, off);
    mu = __shfl(mu, 0) * (1.f / 64.f);
    float d0 = x2p - mu;
    float vv = d0 * d0;
    for (int off = 32; off; off >>= 1) vv += __shfl_down(vv, off);
    vv = __shfl(vv, 0) * (1.f / 64.f);
    float x2 = d0 * rsqrtf(vv + 1e-5f) * ln2_g[c] + ln2_b[c];
    float x1p = b_out[c];
    for (int k = 0; k < 64; k++) x1p += osv[k] * woT[k * 64 + c];
    x1p += q_own;
    float mu1 = x1p;
    for (int off = 32; off; off >>= 1) mu1 += __shfl_down(mu1, off);
    mu1 = __shfl(mu1, 0) * (1.f / 64.f);
    float d1 = x1p - mu1;
    float v1 = d1 * d1;
    for (int off = 32; off; off >>= 1) v1 += __shfl_down(v1, off);
    v1 = __shfl(v1, 0) * (1.f / 64.f);
    float x1 = d1 * rsqrtf(v1 + 1e-5f) * ln1_g[c] + ln1_b[c];
    out[((long)t * 8 + b) * 64 + c] = x1 + x2;
}

// ----------------------------------------------------------------
extern "C" void kernel_launch(void* const* d_in, const int* in_sizes, int n_in,
                              void* d_out, int out_size, void* d_ws, size_t ws_size,
                              hipStream_t stream) {
    const float* tgt       = (const float*)d_in[0];
    const float* memory    = (const float*)d_in[1];
    const float* pos       = (const float*)d_in[2];
    const float* query_pos = (const float*)d_in[3];
    const float* w_in      = (const float*)d_in[4];
    const float* b_in      = (const float*)d_in[5];
    const float* w_out     = (const float*)d_in[6];
    const float* b_out     = (const float*)d_in[7];
    const float* ln1_g     = (const float*)d_in[8];
    const float* ln1_b     = (const float*)d_in[9];
    const float* ln2_g     = (const float*)d_in[10];
    const float* ln2_b     = (const float*)d_in[11];
    const float* dw_w      = (const float*)d_in[12];
    const float* bn1_g     = (const float*)d_in[13];
    const float* bn1_b     = (const float*)d_in[14];
    const float* bn1_m     = (const float*)d_in[15];
    const float* bn1_v     = (const float*)d_in[16];
    const float* pw_w      = (const float*)d_in[17];
    const float* bn2_g     = (const float*)d_in[18];
    const float* bn2_b     = (const float*)d_in[19];
    const float* bn2_m     = (const float*)d_in[20];
    const float* bn2_v     = (const float*)d_in[21];
    const float* mheads    = (const float*)d_in[22];
    const float* m1_lw1 = (const float*)d_in[23];
    const float* m1_lb1 = (const float*)d_in[24];
    const float* m1_lw2 = (const float*)d_in[25];
    const float* m1_lb2 = (const float*)d_in[26];
    const float* m1_gw1 = (const float*)d_in[27];
    const float* m1_gb1 = (const float*)d_in[28];
    const float* m1_gw2 = (const float*)d_in[29];
    const float* m1_gb2 = (const float*)d_in[30];
    const float* m2_lw1 = (const float*)d_in[31];
    const float* m2_lb1 = (const float*)d_in[32];
    const float* m2_lw2 = (const float*)d_in[33];
    const float* m2_lb2 = (const float*)d_in[34];
    const float* m2_gw1 = (const float*)d_in[35];
    const float* m2_gb1 = (const float*)d_in[36];
    const float* m2_gw2 = (const float*)d_in[37];
    const float* m2_gb2 = (const float*)d_in[38];

    float* ws = (float*)d_ws;
    float* out = (float*)d_out;
    unsigned short* keyb = (unsigned short*)(ws + OFF_KEY);
    unsigned short* kph  = (unsigned short*)(ws + OFF_KPH);
    unsigned short* vph  = (unsigned short*)(ws + OFF_VPH);
    unsigned short* wb   = (unsigned short*)(ws + OFF_WB);

    // zero atomic regions (pool + protos + Z, contiguous)
    hipMemsetAsync(ws + OFF_POOL, 0, 8832 * sizeof(float), stream);

    k_stage1<<<4327, 256, 0, stream>>>(memory, pos,
                                       m1_lw1, m1_lw2, w_in, pw_w, mheads, dw_w,
                                       bn1_g, bn1_b, bn1_m, bn1_v,
                                       bn2_g, bn2_b, bn2_m, bn2_v,
                                       m1_gw1, m1_gw2, m2_gw1, m2_gw2,
                                       m2_lw1, m2_lw2, w_out,
                                       tgt, query_pos, b_in,
                                       keyb, ws + OFF_POOL, wb, ws + OFF_CST,
                                       ws + OFF_QP, ws + OFF_QB);
    k_stage2<<<1536, 512, 0, stream>>>(keyb, ws + OFF_POOL,
                                       m1_lb1, m1_lb2, m1_gb1, m1_gb2, b_in,
                                       wb, ws + OFF_CST,
                                       kph, vph, ws + OFF_PROT, ws + OFF_ZZ);
    k_mha<<<512, 256, 0, stream>>>(ws + OFF_QP, kph, vph, ws + OFF_PART);
    k_final<<<128, 64, 0, stream>>>(ws + OFF_QB, ws + OFF_PROT, ws + OFF_ZZ, ws + OFF_PART,
                                    ws + OFF_CST, b_out,
                                    ln1_g, ln1_b, ln2_g, ln2_b,
                                    m2_lb1, m2_lb2, m2_gb1, m2_gb2,
                                    out);
}